// Round 19
// baseline (824.375 us; speedup 1.0000x reference)
//
#include <hip/hip_runtime.h>
#include <hip/hip_bf16.h>
#include <hip/hip_fp16.h>

typedef unsigned short u16;
typedef unsigned char u8;
typedef unsigned int u32;
typedef short s16x8 __attribute__((ext_vector_type(8)));
typedef float f32x4 __attribute__((ext_vector_type(4)));
typedef int i32x4 __attribute__((ext_vector_type(4)));

#define FE_LD 2944
#define EDGE_LD 2816

static __device__ __forceinline__ int sdot4(u32 a, u32 b, int acc) {
  return __builtin_amdgcn_sdot4((int)a, (int)b, acc, false);
}
static __device__ __forceinline__ float fsig(float x) {
  return __builtin_amdgcn_rcpf(1.f + __expf(-x));
}
static __device__ __forceinline__ float ftanh(float x) {
  return 1.f - 2.f * __builtin_amdgcn_rcpf(1.f + __expf(2.f * x));
}
static __device__ __forceinline__ u16 f2bf_raw(float f) {
  return __builtin_bit_cast(u16, __float2bfloat16(f));
}

#define GLD_LDS16(gsrc, ldst) \
  __builtin_amdgcn_global_load_lds((const __attribute__((address_space(1))) void*)(gsrc), \
                                   (__attribute__((address_space(3))) void*)(ldst), 16, 0, 0)

// XCD-aware swizzle: 1-D grid (nwg % 8 == 0).
static __device__ __forceinline__ void xcd_map(int gy, int* bx, int* by) {
  int lin = blockIdx.x;
  int q = gridDim.x >> 3;
  int wg = (lin & 7) * q + (lin >> 3);
  *bx = wg / gy; *by = wg % gy;
}

// ---------------------------------------------------------------------------
// bf16 MFMA GEMM (unchanged)
// ---------------------------------------------------------------------------
__global__ __launch_bounds__(256) void gemm_kernel(
    const u16* __restrict__ A, int lda,
    const u16* __restrict__ B, int ldb,
    int K, int N, int gy,
    float* __restrict__ outF, __hip_bfloat16* __restrict__ outB, int ldc,
    const float* __restrict__ bias)
{
  __shared__ __align__(16) u16 As[128*64];
  __shared__ __align__(16) u16 Bs[128*64];
  const int tid = threadIdx.x;
  const int w = tid >> 6, lane = tid & 63;
  const int wm = w >> 1, wn = w & 1;
  int bxi, byi; xcd_map(gy, &bxi, &byi);
  const long bm = (long)bxi * 128;
  const long bn = (long)byi * 128;
  f32x4 acc[4][4] = {};

  for (int k0 = 0; k0 < K; k0 += 64) {
    #pragma unroll
    for (int rr = 0; rr < 4; rr++) {
      int idx = rr * 256 + tid;
      int row = idx >> 3;
      int g   = idx & 7;
      int gs  = g ^ (row & 7);
      int ldst = (rr * 256 + (w << 6)) * 8;
      GLD_LDS16(A + (bm + row) * (long)lda + k0 + gs * 8, &As[ldst]);
      GLD_LDS16(B + (bn + row) * (long)ldb + k0 + gs * 8, &Bs[ldst]);
    }
    __syncthreads();
    #pragma unroll
    for (int kk = 0; kk < 2; kk++) {
      s16x8 af[4], bfr[4];
      #pragma unroll
      for (int i = 0; i < 4; i++) {
        int ra = wm * 64 + i * 16 + (lane & 15);
        int rb = wn * 64 + i * 16 + (lane & 15);
        int gg = kk * 4 + (lane >> 4);
        af[i]  = *(const s16x8*)&As[ra * 64 + ((gg ^ (ra & 7)) << 3)];
        bfr[i] = *(const s16x8*)&Bs[rb * 64 + ((gg ^ (rb & 7)) << 3)];
      }
      #pragma unroll
      for (int i = 0; i < 4; i++)
        #pragma unroll
        for (int j = 0; j < 4; j++)
          acc[i][j] = __builtin_amdgcn_mfma_f32_16x16x32_bf16(af[i], bfr[j], acc[i][j], 0, 0, 0);
    }
    __syncthreads();
  }

  #pragma unroll
  for (int i = 0; i < 4; i++)
    #pragma unroll
    for (int j = 0; j < 4; j++)
      #pragma unroll
      for (int v = 0; v < 4; v++) {
        long rr = bm + wm * 64 + i * 16 + (lane >> 4) * 4 + v;
        int  cc = (int)bn + wn * 64 + j * 16 + (lane & 15);
        if (cc < N) {
          float val = acc[i][j][v] + (bias ? bias[cc] : 0.f);
          if (outF) outF[rr * (long)ldc + cc] = val;
          else      outB[rr * (long)ldc + cc] = __float2bfloat16(val);
        }
      }
}

// ---------------------------------------------------------------------------
// i8 MFMA GEMM (unchanged)
// ---------------------------------------------------------------------------
__global__ __launch_bounds__(256) void gemm_i8_kernel(
    const u8* __restrict__ A, int lda,
    const u8* __restrict__ B, int ldb,
    int K, int N, int gy,
    const float* __restrict__ asc, const float* __restrict__ bsc,
    __hip_bfloat16* __restrict__ outB, int ldc,
    const float* __restrict__ bias)
{
  __shared__ __align__(16) u8 As[128*128];
  __shared__ __align__(16) u8 Bs[128*128];
  const int tid = threadIdx.x;
  const int w = tid >> 6, lane = tid & 63;
  const int wm = w >> 1, wn = w & 1;
  int bxi, byi; xcd_map(gy, &bxi, &byi);
  const long bm = (long)bxi * 128;
  const long bn = (long)byi * 128;
  i32x4 acc[4][4] = {};

  for (int k0 = 0; k0 < K; k0 += 128) {
    #pragma unroll
    for (int rr = 0; rr < 4; rr++) {
      int idx = rr * 256 + tid;
      int row = idx >> 3;
      int g   = idx & 7;
      int gs  = g ^ (row & 7);
      int ldst = (rr * 256 + (w << 6)) * 16;
      GLD_LDS16(A + (bm + row) * (long)lda + k0 + gs * 16, &As[ldst]);
      GLD_LDS16(B + (bn + row) * (long)ldb + k0 + gs * 16, &Bs[ldst]);
    }
    __syncthreads();
    #pragma unroll
    for (int kk = 0; kk < 2; kk++) {
      i32x4 af[4], bfr[4];
      #pragma unroll
      for (int i = 0; i < 4; i++) {
        int ra = wm * 64 + i * 16 + (lane & 15);
        int rb = wn * 64 + i * 16 + (lane & 15);
        int gg = kk * 4 + (lane >> 4);
        af[i]  = __builtin_bit_cast(i32x4, *(const uint4*)&As[ra * 128 + ((gg ^ (ra & 7)) << 4)]);
        bfr[i] = __builtin_bit_cast(i32x4, *(const uint4*)&Bs[rb * 128 + ((gg ^ (rb & 7)) << 4)]);
      }
      #pragma unroll
      for (int i = 0; i < 4; i++)
        #pragma unroll
        for (int j = 0; j < 4; j++)
          acc[i][j] = __builtin_amdgcn_mfma_i32_16x16x64_i8(af[i], bfr[j], acc[i][j], 0, 0, 0);
    }
    __syncthreads();
  }

  #pragma unroll
  for (int i = 0; i < 4; i++)
    #pragma unroll
    for (int j = 0; j < 4; j++)
      #pragma unroll
      for (int v = 0; v < 4; v++) {
        long rr = bm + wm * 64 + i * 16 + (lane >> 4) * 4 + v;
        int  cc = (int)bn + wn * 64 + j * 16 + (lane & 15);
        if (cc < N) {
          float val = (float)acc[i][j][v] * asc[rr] * bsc[cc] + (bias ? bias[cc] : 0.f);
          outB[rr * (long)ldc + cc] = __float2bfloat16(val);
        }
      }
}

// ---------------------------------------------------------------------------
// Launch A: [colmax partials (128) | whh packs (32) | prep rows (4096)].
// colmax: partial[set][ks][r] = max |w[d][k][c]| over k-slice ks (coalesced).
// ---------------------------------------------------------------------------
struct PrepA {
  const float* objw; const float* edgew;      // wih0 fp32 sources
  float* partial;                             // [2][8][2048]
  const float* whh[4];
  u32* wreg[4]; u32* wlds[4]; float* wsc[4];
  const float* logits; const float* fmaps; const float* boxes;
  const float* bn_g; const float* bn_b; const float* bn_m; const float* bn_v;
  const float* pos_w; const float* pos_b; const float* embw;
  __hip_bfloat16* FE; u8* FEq; float* ascFE; float* conf;
};
__global__ __launch_bounds__(256) void prepA_kernel(PrepA ops)
{
  __shared__ __align__(16) float stage[2432];
  __shared__ float red[256];
  __shared__ float pf[151];
  const int bid = blockIdx.x, t = threadIdx.x;

  if (bid < 128) {                       // colmax partials
    const int set = bid >> 6;
    const int b6 = bid & 63;
    const int cb = b6 & 7, ks = b6 >> 3;
    const int r = cb * 256 + t;          // 0..2047
    const int d = r >> 10, c = r & 1023;
    const int K = set ? 2760 : 2376;
    const int K8 = K / 8;
    const float* src = (set ? ops.edgew : ops.objw) + (size_t)d * K * 1024 + c;
    float m = 0.f;
    for (int k = ks * K8; k < (ks + 1) * K8; k++)
      m = fmaxf(m, fabsf(src[(size_t)k * 1024]));
    ops.partial[(size_t)set * 16384 + ks * 2048 + r] = m;
    return;
  }

  if (bid < 160) {                       // whh packs
    const int local = bid - 128;
    const int set = local >> 3;
    const int idx = (local & 7) * 256 + t;
    const float* whh = ops.whh[set];
    u32* wreg = ops.wreg[set];
    u32* wlds = ops.wlds[set];
    float* wsc = ops.wsc[set];
    const int d = idx >> 10, col = idx & 1023;
    const int c4 = col >> 8, j = col & 255;
    const float* s = whh + (size_t)d * 256 * 1024 + col;
    float mx = 0.f;
    for (int k = 0; k < 256; k++) mx = fmaxf(mx, fabsf(s[(size_t)k * 1024]));
    float inv = (mx > 0.f) ? 127.f / mx : 0.f;
    wsc[d * 1024 + col] = (mx > 0.f) ? mx / (127.f * 127.f) : 0.f;
    const int rc = (c4 < 2) ? 12 : 8;
    const int rb = (c4 == 0) ? 0 : (c4 == 1) ? 12 : (c4 == 2) ? 24 : 32;
    for (int kg = 0; kg < 4; kg++) {
      const int slot = kg * 256 + j;
      for (int w = 0; w < 16; w++) {
        u32 v = 0;
        #pragma unroll
        for (int b = 0; b < 4; b++) {
          int q = __float2int_rn(s[(size_t)(kg * 64 + 4 * w + b) * 1024] * inv);
          q = max(-127, min(127, q));
          v |= ((u32)(q & 0xff)) << (8 * b);
        }
        if (w < rc) {
          wreg[(size_t)(d * 40 + rb + w) * 1024 + slot] = v;
        } else {
          int qq, comp;
          if (c4 == 0)      { qq = 0; comp = w - 12; }
          else if (c4 == 1) { qq = 1; comp = w - 12; }
          else if (c4 == 2) { qq = 2 + ((w - 8) >> 2); comp = (w - 8) & 3; }
          else              { qq = 4 + ((w - 8) >> 2); comp = (w - 8) & 3; }
          wlds[((size_t)(d * 6 + qq) * 1024 + slot) * 4 + comp] = v;
        }
      }
    }
    return;
  }

  // ---- prep rows ----
  const int row = bid - 160;
  float v = (t < 151) ? ops.logits[(size_t)row * 151 + t] : -3.0e38f;
  red[t] = v; __syncthreads();
  for (int s = 128; s > 0; s >>= 1) { if (t < s) red[t] = fmaxf(red[t], red[t + s]); __syncthreads(); }
  float mx = red[0]; __syncthreads();
  float p = (t < 151) ? expf(v - mx) : 0.f;
  red[t] = p; __syncthreads();
  for (int s = 128; s > 0; s >>= 1) { if (t < s) red[t] += red[t + s]; __syncthreads(); }
  float sum = red[0]; __syncthreads();
  p = p / sum;
  if (t < 151) pf[t] = p;
  red[t] = (t >= 1 && t < 151) ? p : 0.f; __syncthreads();
  for (int s = 128; s > 0; s >>= 1) { if (t < s) red[t] = fmaxf(red[t], red[t + s]); __syncthreads(); }
  if (t == 0) ops.conf[row] = red[0];
  __syncthreads();

  __hip_bfloat16* FE = ops.FE + (size_t)row * FE_LD;
  {
    const float4* fm4 = (const float4*)(ops.fmaps + (size_t)row * 2048);
    for (int q4 = t; q4 < 512; q4 += 256) {
      float4 f = fm4[q4];
      *(float4*)&stage[q4 * 4] = f;
      ushort4 h;
      h.x = f2bf_raw(f.x); h.y = f2bf_raw(f.y); h.z = f2bf_raw(f.z); h.w = f2bf_raw(f.w);
      *(ushort4*)&FE[512 + q4 * 4] = h;
    }
  }
  if (t < 50) {
    const float4* ew4 = (const float4*)(ops.embw);
    float4 e = {0.f, 0.f, 0.f, 0.f};
    for (int k = 0; k < 151; k++) {
      float4 w = ew4[k * 50 + t];
      float pk = pf[k];
      e.x += pk * w.x; e.y += pk * w.y; e.z += pk * w.z; e.w += pk * w.w;
    }
    *(float4*)&stage[2048 + 4 * t] = e;
    ushort4 h;
    h.x = f2bf_raw(e.x); h.y = f2bf_raw(e.y); h.z = f2bf_raw(e.z); h.w = f2bf_raw(e.w);
    *(ushort4*)&FE[2560 + 4 * t] = h;
  }
  if (t < 128) {
    float x1 = ops.boxes[row * 4 + 0], y1 = ops.boxes[row * 4 + 1];
    float x2 = ops.boxes[row * 4 + 2], y2 = ops.boxes[row * 4 + 3];
    float cs[4] = { (x1 + x2) * 0.5f, (y1 + y2) * 0.5f, x2 - x1, y2 - y1 };
    float a = ops.pos_b[t];
    #pragma unroll
    for (int j = 0; j < 4; j++) {
      float cn = (cs[j] - ops.bn_m[j]) * rsqrtf(ops.bn_v[j] + 1e-5f) * ops.bn_g[j] + ops.bn_b[j];
      a += cn * ops.pos_w[j * 128 + t];
    }
    a = fmaxf(a, 0.f);
    stage[2248 + t] = a;
    FE[2760 + t] = __float2bfloat16(a);
  }
  if (t < 56) { stage[2376 + t] = 0.f; FE[2888 + t] = __float2bfloat16(0.f); }
  __syncthreads();

  float qm = 0.f;
  for (int c = t; c < 2432; c += 256) qm = fmaxf(qm, fabsf(stage[c]));
  red[t] = qm; __syncthreads();
  for (int s = 128; s > 0; s >>= 1) { if (t < s) red[t] = fmaxf(red[t], red[t + s]); __syncthreads(); }
  qm = red[0];
  float inv = (qm > 0.f) ? 127.f / qm : 0.f;
  if (t == 0) ops.ascFE[row] = (qm > 0.f) ? qm / 127.f : 0.f;
  u32* d32 = (u32*)(ops.FEq + (size_t)row * 2432);
  for (int wd = t; wd < 608; wd += 256) {
    u32 vv = 0;
    #pragma unroll
    for (int b = 0; b < 4; b++) {
      int q = __float2int_rn(stage[4 * wd + b] * inv);
      q = max(-127, min(127, q));
      vv |= ((u32)(q & 0xff)) << (8 * b);
    }
    d32[wd] = vv;
  }
}

// ---------------------------------------------------------------------------
// Launch B: transposes (i8-direct for wih0/ewih0; bf16 for the rest) + sort.
// i8 tile: 128 k x 64 n; bf16 tile: 64 x 64 (scalar conflict-free writes).
// ---------------------------------------------------------------------------
#define N_OPS 9
struct Setup2 {
  const float* src[N_OPS];      // fp32 source (d-offset applied)
  void* dst[N_OPS];             // u8* (i8) or bf16*
  const float* partial[N_OPS];  // i8 only: [8][2048] set base
  float* bscOut[N_OPS];         // i8 only
  int rowBase[N_OPS];           // i8 only: d*1024
  int srcK[N_OPS], srcN[N_OPS], dstR[N_OPS], dstC[N_OPS];
  int split[N_OPS], soff[N_OPS], isI8[N_OPS];
  int tileBase[N_OPS], tilesX[N_OPS];
  int trEnd;
  const float* conf; int* perm;
};
__global__ __launch_bounds__(256) void setup2_kernel(Setup2 ops)
{
  const int bid = blockIdx.x, t = threadIdx.x;
  if (bid < ops.trEnd) {
    __shared__ float tile[128 * 65];
    __shared__ float invr[64];
    int op = 0;
    #pragma unroll
    for (int i = 1; i < N_OPS; i++) if (bid >= ops.tileBase[i]) op = i;
    const int local = bid - ops.tileBase[op];
    const float* src = ops.src[op];
    const int srcK = ops.srcK[op], srcN = ops.srcN[op];
    const int dstC = ops.dstC[op];

    if (ops.isI8[op]) {
      const int kt = (local % ops.tilesX[op]) * 128;
      const int nt = (local / ops.tilesX[op]) * 64;
      u8* dst = (u8*)ops.dst[op];
      // read 128 k-rows x 64 n-cols
      const int tx = t & 63, ty = t >> 6;
      #pragma unroll
      for (int i0 = 0; i0 < 32; i0++) {
        int k = i0 * 4 + ty;
        int srck = kt + k;
        tile[k * 65 + tx] = (srck < srcK) ? src[(size_t)srck * srcN + nt + tx] : 0.f;
      }
      // per-row scale from partials
      if (t < 64) {
        int g = ops.rowBase[op] + nt + t;
        const float* pp = ops.partial[op];
        float m = pp[g];
        #pragma unroll
        for (int s = 1; s < 8; s++) m = fmaxf(m, pp[s * 2048 + g]);
        invr[t] = (m > 0.f) ? 127.f / m : 0.f;
        if (kt == 0) ops.bscOut[op][g] = (m > 0.f) ? m / 127.f : 0.f;
      }
      __syncthreads();
      // write: 8 n-rows per pass x 32 k-quads
      const int k4 = t & 31, ng = t >> 5;
      #pragma unroll
      for (int pass = 0; pass < 8; pass++) {
        int nl = pass * 8 + ng;
        float inv = invr[nl];
        u32 vv = 0;
        #pragma unroll
        for (int j = 0; j < 4; j++) {
          int q = __float2int_rn(tile[(4 * k4 + j) * 65 + nl] * inv);
          q = max(-127, min(127, q));
          vv |= ((u32)(q & 0xff)) << (8 * j);
        }
        *(u32*)&dst[(size_t)(nt + nl) * dstC + kt + 4 * k4] = vv;
      }
    } else {
      const int kt = (local % ops.tilesX[op]) * 64;
      const int nt = (local / ops.tilesX[op]) * 64;
      __hip_bfloat16* dst = (__hip_bfloat16*)ops.dst[op];
      const int dstR = ops.dstR[op];
      const int split = ops.split[op], soff = ops.soff[op];
      const int tx = t & 63, ty = t >> 6;
      #pragma unroll
      for (int i0 = 0; i0 < 16; i0++) {
        int i = i0 * 4 + ty;
        int k = kt + i;
        int srck = (k < split) ? (soff + k) : (k - split);
        int n = nt + tx;
        tile[i * 65 + tx] = (srck < srcK && n < srcN) ? src[(size_t)srck * srcN + n] : 0.f;
      }
      __syncthreads();
      #pragma unroll
      for (int i0 = 0; i0 < 16; i0++) {
        int i = i0 * 4 + ty;
        int n = nt + i, k = kt + tx;
        if (n < dstR && k < dstC)
          dst[(size_t)n * dstC + k] = __float2bfloat16(tile[tx * 65 + i]);
      }
    }
    return;
  }
  {
    __shared__ float key[128];
    __shared__ int   idx[128];
    const int b = bid - ops.trEnd;
    if (t < 128) { key[t] = ops.conf[b * 128 + t]; idx[t] = t; }
    __syncthreads();
    for (int k = 2; k <= 128; k <<= 1)
      for (int j = k >> 1; j > 0; j >>= 1) {
        if (t < 128) {
          int ixj = t ^ j;
          if (ixj > t) {
            bool up = (t & k) == 0;
            float ka = key[t], kb = key[ixj];
            int ia = idx[t], ib = idx[ixj];
            bool before = (ka > kb) || (ka == kb && ia < ib);
            if (before != up) { key[t] = kb; key[ixj] = ka; idx[t] = ib; idx[ixj] = ia; }
          }
        }
        __syncthreads();
      }
    if (t < 128) ops.perm[b * 128 + t] = b * 128 + idx[t];
  }
}

// ---------------------------------------------------------------------------
// LSTM scan (unchanged R12 structure).
// ---------------------------------------------------------------------------
__global__ __launch_bounds__(1024) void rec_kernel(
    const __hip_bfloat16* __restrict__ P,
    const int* __restrict__ perm,
    const u32* __restrict__ wreg_g,
    const uint4* __restrict__ wlds_g,
    const float* __restrict__ wsc_g,
    int gatherPerm, int outPerm,
    __hip_bfloat16* __restrict__ out_bf, int out_ld,
    float* __restrict__ out_f32, int f32_ld, int f32_off)
{
  __shared__ __align__(16) uint4 wt4[6 * 1024];
  __shared__ __align__(16) int4 part[256 * 5];
  __shared__ __align__(16) u32 hq[64];
  __shared__ int prow_lds[128];
  const int tid = threadIdx.x;
  const int kg = tid >> 8;
  const int img = blockIdx.x & 31, dir = blockIdx.x >> 5;

  u32 wv[40];
  {
    const u32* rp = wreg_g + (size_t)dir * 40960 + tid;
    #pragma unroll
    for (int i = 0; i < 40; i++) wv[i] = rp[(size_t)i * 1024];
  }
  #pragma unroll
  for (int i = 0; i < 40; i++) asm volatile("" : "+v"(wv[i]));
  {
    const uint4* lp = wlds_g + (size_t)dir * 6144 + tid;
    #pragma unroll
    for (int q = 0; q < 6; q++) wt4[q * 1024 + tid] = lp[(size_t)q * 1024];
  }
  if (tid < 128) prow_lds[tid] = perm[img * 128 + tid];
  if (tid < 64) hq[tid] = 0;

  float sc0 = 0.f, sc1 = 0.f, sc2 = 0.f, sc3 = 0.f, cst = 0.f;
  if (tid < 256) {
    const float* sp = wsc_g + dir * 1024 + tid;
    sc0 = sp[0]; sc1 = sp[256]; sc2 = sp[512]; sc3 = sp[768];
  }
  __syncthreads();

  const uint4* hq4 = (const uint4*)hq;

  int st = dir ? 127 : 0;
  float p0 = 0.f, p1 = 0.f, p2 = 0.f, p3 = 0.f;
  if (tid < 256) {
    int prow0 = gatherPerm ? prow_lds[st] : (img * 128 + st);
    const __hip_bfloat16* pp = P + (size_t)prow0 * 2048 + dir * 1024 + tid;
    p0 = __bfloat162float(pp[0]);   p1 = __bfloat162float(pp[256]);
    p2 = __bfloat162float(pp[512]); p3 = __bfloat162float(pp[768]);
  }

  for (int t = 0; t < 128; t++) {
    float n0 = 0.f, n1 = 0.f, n2 = 0.f, n3 = 0.f;
    if (tid < 256 && t < 127) {
      int stn = dir ? (126 - t) : (t + 1);
      int prn = gatherPerm ? prow_lds[stn] : (img * 128 + stn);
      const __hip_bfloat16* pp = P + (size_t)prn * 2048 + dir * 1024 + tid;
      n0 = __bfloat162float(pp[0]);   n1 = __bfloat162float(pp[256]);
      n2 = __bfloat162float(pp[512]); n3 = __bfloat162float(pp[768]);
    }

    int a0 = 0, a1 = 0, a2 = 0, a3 = 0;
    {
      uint4 hv = hq4[kg * 4 + 0];
      a0 = sdot4(hv.x, wv[0], a0);  a0 = sdot4(hv.y, wv[1], a0);
      a0 = sdot4(hv.z, wv[2], a0);  a0 = sdot4(hv.w, wv[3], a0);
      a1 = sdot4(hv.x, wv[12], a1); a1 = sdot4(hv.y, wv[13], a1);
      a1 = sdot4(hv.z, wv[14], a1); a1 = sdot4(hv.w, wv[15], a1);
      a2 = sdot4(hv.x, wv[24], a2); a2 = sdot4(hv.y, wv[25], a2);
      a2 = sdot4(hv.z, wv[26], a2); a2 = sdot4(hv.w, wv[27], a2);
      a3 = sdot4(hv.x, wv[32], a3); a3 = sdot4(hv.y, wv[33], a3);
      a3 = sdot4(hv.z, wv[34], a3); a3 = sdot4(hv.w, wv[35], a3);
    }
    {
      uint4 hv = hq4[kg * 4 + 1];
      a0 = sdot4(hv.x, wv[4], a0);  a0 = sdot4(hv.y, wv[5], a0);
      a0 = sdot4(hv.z, wv[6], a0);  a0 = sdot4(hv.w, wv[7], a0);
      a1 = sdot4(hv.x, wv[16], a1); a1 = sdot4(hv.y, wv[17], a1);
      a1 = sdot4(hv.z, wv[18], a1); a1 = sdot4(hv.w, wv[19], a1);
      a2 = sdot4(hv.x, wv[28], a2); a2 = sdot4(hv.y, wv[29], a2);
      a2 = sdot4(hv.z, wv[30], a2); a2 = sdot4(hv.w, wv[31], a2);
      a3 = sdot4(hv.x, wv[36], a3); a3 = sdot4(hv.y, wv[37], a3);
      a3 = sdot4(hv.z, wv[38], a3); a3 = sdot4(hv.w, wv[39], a3);
    }
    {
      uint4 hv = hq4[kg * 4 + 2];
      a0 = sdot4(hv.x, wv[8], a0);  a0 = sdot4(hv.y, wv[9], a0);
      a0 = sdot4(hv.z, wv[10], a0); a0 = sdot4(hv.w, wv[11], a0);
      a1 = sdot4(hv.x, wv[20], a1); a1 = sdot4(hv.y, wv[21], a1);
      a1 = sdot4(hv.z, wv[22], a1); a1 = sdot4(hv.w, wv[23], a1);
      uint4 wl = wt4[2 * 1024 + tid];
      a2 = sdot4(hv.x, wl.x, a2); a2 = sdot4(hv.y, wl.y, a2);
      a2 = sdot4(hv.z, wl.z, a2); a2 = sdot4(hv.w, wl.w, a2);
      wl = wt4[4 * 1024 + tid];
      a3 = sdot4(hv.x, wl.x, a3); a3 = sdot4(hv.y, wl.y, a3);
      a3 = sdot4(hv.z, wl.z, a3); a3 = sdot4(hv.w, wl.w, a3);
    }
    {
      uint4 hv = hq4[kg * 4 + 3];
      uint4 wl = wt4[0 * 1024 + tid];
      a0 = sdot4(hv.x, wl.x, a0); a0 = sdot4(hv.y, wl.y, a0);
      a0 = sdot4(hv.z, wl.z, a0); a0 = sdot4(hv.w, wl.w, a0);
      wl = wt4[1 * 1024 + tid];
      a1 = sdot4(hv.x, wl.x, a1); a1 = sdot4(hv.y, wl.y, a1);
      a1 = sdot4(hv.z, wl.z, a1); a1 = sdot4(hv.w, wl.w, a1);
      wl = wt4[3 * 1024 + tid];
      a2 = sdot4(hv.x, wl.x, a2); a2 = sdot4(hv.y, wl.y, a2);
      a2 = sdot4(hv.z, wl.z, a2); a2 = sdot4(hv.w, wl.w, a2);
      wl = wt4[5 * 1024 + tid];
      a3 = sdot4(hv.x, wl.x, a3); a3 = sdot4(hv.y, wl.y, a3);
      a3 = sdot4(hv.z, wl.z, a3); a3 = sdot4(hv.w, wl.w, a3);
    }

    part[(tid & 255) * 5 + kg] = int4{a0, a1, a2, a3};
    __syncthreads();

    if (tid < 256) {
      int4 q0 = part[tid * 5 + 0], q1 = part[tid * 5 + 1];
      int4 q2 = part[tid * 5 + 2], q3 = part[tid * 5 + 3];
      float gi = (float)(q0.x + q1.x + q2.x + q3.x) * sc0 + p0;
      float gf = (float)(q0.y + q1.y + q2.y + q3.y) * sc1 + p1;
      float gg = (float)(q0.z + q1.z + q2.z + q3.z) * sc2 + p2;
      float go = (float)(q0.w + q1.w + q2.w + q3.w) * sc3 + p3;
      float si = fsig(gi), sf = fsig(gf), so = fsig(go);
      cst = sf * cst + si * ftanh(gg);
      float h = so * ftanh(cst);
      int qi = __float2int_rn(h * 127.f);
      ((signed char*)hq)[tid] = (signed char)qi;
      const int orow = outPerm ? prow_lds[st] : (img * 128 + st);
      if (out_bf)  out_bf[(size_t)orow * out_ld + dir * 256 + tid] = __float2bfloat16(h);
      if (out_f32) out_f32[(size_t)orow * f32_ld + f32_off + dir * 256 + tid] = h;
    }
    __syncthreads();
    p0 = n0; p1 = n1; p2 = n2; p3 = n3;
    st = dir ? (st - 1) : (st + 1);
  }
}

// ---------------------------------------------------------------------------
// Fused argmax + edge-row build + i8 quant (vectorized loads).
// ---------------------------------------------------------------------------
__global__ __launch_bounds__(256) void argmax_edge_kernel(
    const float* __restrict__ dists,
    const float* __restrict__ embed2,
    const float* __restrict__ fmaps,
    const __hip_bfloat16* __restrict__ FE,
    u8* __restrict__ EDGEq, float* __restrict__ ascEDGE)
{
  __shared__ __align__(16) float stage[EDGE_LD];
  __shared__ float rv[256];
  __shared__ int   ri[256];
  const int row = blockIdx.x, t = threadIdx.x;

  float best = (t < 150) ? dists[(size_t)row * 663 + 1 + t] : -3.4e38f;
  int   bi   = (t < 150) ? (1 + t) : 1000;
  rv[t] = best; ri[t] = bi;
  __syncthreads();
  for (int s = 128; s > 0; s >>= 1) {
    if (t < s) {
      float ov = rv[t + s]; int oi = ri[t + s];
      if (ov > rv[t] || (ov == rv[t] && oi < ri[t])) { rv[t] = ov; ri[t] = oi; }
    }
    __syncthreads();
  }
  const int pr = ri[0];

  for (int c0 = t; c0 < 200; c0 += 256)
    stage[c0] = embed2[(size_t)pr * 200 + c0];
  if (t < 64) {
    const uint4* e4 = (const uint4*)(FE + (size_t)row * FE_LD);
    uint4 v = e4[t];
    #pragma unroll
    for (int wi = 0; wi < 4; wi++) {
      u32 w = (wi == 0) ? v.x : (wi == 1) ? v.y : (wi == 2) ? v.z : v.w;
      stage[200 + t * 8 + wi * 2]     = __builtin_bit_cast(float, w << 16);
      stage[200 + t * 8 + wi * 2 + 1] = __builtin_bit_cast(float, w & 0xffff0000u);
    }
  }
  {
    const float4* fm4 = (const float4*)(fmaps + (size_t)row * 2048);
    for (int c4 = t; c4 < 512; c4 += 256)
      *(float4*)&stage[712 + c4 * 4] = fm4[c4];
  }
  if (t < 56) stage[2760 + t] = 0.f;
  __syncthreads();

  float qm = 0.f;
  for (int c = t; c < EDGE_LD; c += 256) qm = fmaxf(qm, fabsf(stage[c]));
  rv[t] = qm; __syncthreads();
  for (int s = 128; s > 0; s >>= 1) { if (t < s) rv[t] = fmaxf(rv[t], rv[t + s]); __syncthreads(); }
  qm = rv[0];
  float inv = (qm > 0.f) ? 127.f / qm : 0.f;
  if (t == 0) ascEDGE[row] = (qm > 0.f) ? qm / 127.f : 0.f;
  uint2* d64 = (uint2*)(EDGEq + (size_t)row * EDGE_LD);
  for (int wd8 = t; wd8 < (EDGE_LD >> 3); wd8 += 256) {
    u32 out[2] = {0, 0};
    #pragma unroll
    for (int b = 0; b < 8; b++) {
      int q = __float2int_rn(stage[8 * wd8 + b] * inv);
      q = max(-127, min(127, q));
      out[b >> 2] |= ((u32)(q & 0xff)) << (8 * (b & 3));
    }
    d64[wd8] = uint2{out[0], out[1]};
  }
}

// ---------------------------------------------------------------------------
extern "C" void kernel_launch(void* const* d_in, const int* in_sizes, int n_in,
                              void* d_out, int out_size, void* d_ws, size_t ws_size,
                              hipStream_t stream)
{
  const float* obj_fmaps    = (const float*)d_in[0];
  const float* obj_logits   = (const float*)d_in[1];
  const float* boxes        = (const float*)d_in[2];
  const float* obj_embed_w  = (const float*)d_in[4];
  const float* obj_embed2_w = (const float*)d_in[5];
  const float* bn_g = (const float*)d_in[6];
  const float* bn_b = (const float*)d_in[7];
  const float* bn_m = (const float*)d_in[8];
  const float* bn_v = (const float*)d_in[9];
  const float* pos_w = (const float*)d_in[10];
  const float* pos_b = (const float*)d_in[11];
  const float* obj_wih0 = (const float*)d_in[12];
  const float* obj_whh0 = (const float*)d_in[13];
  const float* obj_b0   = (const float*)d_in[14];
  const float* obj_wih1 = (const float*)d_in[15];
  const float* obj_whh1 = (const float*)d_in[16];
  const float* obj_b1   = (const float*)d_in[17];
  const float* edge_wih0 = (const float*)d_in[18];
  const float* edge_whh0 = (const float*)d_in[19];
  const float* edge_b0   = (const float*)d_in[20];
  const float* edge_wih1 = (const float*)d_in[21];
  const float* edge_whh1 = (const float*)d_in[22];
  const float* edge_b1   = (const float*)d_in[23];
  const float* dec_w = (const float*)d_in[24];
  const float* dec_b = (const float*)d_in[25];
  float* out = (float*)d_out;

  char* ws = (char*)d_ws;
  auto alloc = [&](size_t bytes) -> char* {
    char* p = ws; ws += (bytes + 255) & ~(size_t)255; return p;
  };
  __hip_bfloat16* FE     = (__hip_bfloat16*)alloc(4096ull * FE_LD * 2);
  __hip_bfloat16* Pbuf   = (__hip_bfloat16*)alloc(4096ull * 2048 * 2);
  __hip_bfloat16* hseq   = (__hip_bfloat16*)alloc(4096ull * 512 * 2);
  __hip_bfloat16* wih1T  = (__hip_bfloat16*)alloc(2048ull * 512 * 2);
  __hip_bfloat16* ewih1T = (__hip_bfloat16*)alloc(2048ull * 512 * 2);
  __hip_bfloat16* decT   = (__hip_bfloat16*)alloc(256ull * 2944 * 2);
  u32* whh0pk  = (u32*)alloc(133120ull * 4);
  u32* whh1pk  = (u32*)alloc(133120ull * 4);
  u32* ewhh0pk = (u32*)alloc(133120ull * 4);
  u32* ewhh1pk = (u32*)alloc(133120ull * 4);
  u8*  FEq     = (u8*)alloc(4096ull * 2432);
  u8*  EDGEq   = (u8*)alloc(4096ull * 2816);
  u8*  wih0q   = (u8*)alloc(2048ull * 2432);
  u8*  ewih0q  = (u8*)alloc(2048ull * 2816);
  float* partial = (float*)alloc(2ull * 8 * 2048 * 4);
  float* ascFE   = (float*)alloc(4096 * 4);
  float* ascEDGE = (float*)alloc(4096 * 4);
  float* bsc0    = (float*)alloc(2048 * 4);
  float* bsc1    = (float*)alloc(2048 * 4);
  int*   perm  = (int*)alloc(4096 * 4);
  float* conf  = (float*)alloc(4096 * 4);
  (void)in_sizes; (void)n_in; (void)out_size; (void)ws_size;

  // ---- Launch A ----
  PrepA pa{};
  pa.objw = obj_wih0; pa.edgew = edge_wih0; pa.partial = partial;
  const float* whhs[4] = {obj_whh0, obj_whh1, edge_whh0, edge_whh1};
  u32* pks[4] = {whh0pk, whh1pk, ewhh0pk, ewhh1pk};
  for (int i = 0; i < 4; i++) {
    pa.whh[i] = whhs[i];
    pa.wreg[i] = pks[i];
    pa.wlds[i] = pks[i] + 81920;
    pa.wsc[i]  = (float*)(pks[i] + 131072);
  }
  pa.logits = obj_logits; pa.fmaps = obj_fmaps; pa.boxes = boxes;
  pa.bn_g = bn_g; pa.bn_b = bn_b; pa.bn_m = bn_m; pa.bn_v = bn_v;
  pa.pos_w = pos_w; pa.pos_b = pos_b; pa.embw = obj_embed_w;
  pa.FE = FE; pa.FEq = FEq; pa.ascFE = ascFE; pa.conf = conf;
  prepA_kernel<<<dim3(160 + 4096), dim3(256), 0, stream>>>(pa);

  // ---- Launch B ----
  Setup2 s2{};
  int nOps = 0, base = 0;
  auto addI8 = [&](const float* src, u8* dst, const float* part, float* bsc,
                   int rowBase, int srcK, int dstC) {
    int i = nOps++;
    s2.src[i] = src; s2.dst[i] = dst; s2.partial[i] = part; s2.bscOut[i] = bsc;
    s2.rowBase[i] = rowBase;
    s2.srcK[i] = srcK; s2.srcN[i] = 1024; s2.dstR[i] = 1024; s2.dstC[i] = dstC;
    s2.split[i] = 0; s2.soff[i] = 0; s2.isI8[i] = 1;
    s2.tileBase[i] = base; s2.tilesX[i] = dstC / 128;
    base += (dstC / 128) * (1024 / 64);
  };
  auto addBf = [&](const float* src, __hip_bfloat16* dst, int srcK, int srcN,
                   int dstR, int dstC, int split, int soff) {
    int i = nOps++;
    s2.src[i] = src; s2.dst[i] = dst; s2.partial[i] = nullptr; s2.bscOut[i] = nullptr;
    s2.rowBase[i] = 0;
    s2.srcK[i] = srcK; s2.srcN[i] = srcN; s2.dstR[i] = dstR; s2.dstC[i] = dstC;
    s2.split[i] = split; s2.soff[i] = soff; s2.isI8[i] = 0;
    int tx = (dstC + 63) / 64, ty = (dstR + 63) / 64;
    s2.tileBase[i] = base; s2.tilesX[i] = tx;
    base += tx * ty;
  };
  for (int d = 0; d < 2; d++)
    addI8(obj_wih0 + (size_t)d * 2376 * 1024, wih0q + (size_t)d * 1024 * 2432,
          partial, bsc0, d * 1024, 2376, 2432);
  for (int d = 0; d < 2; d++)
    addI8(edge_wih0 + (size_t)d * 2760 * 1024, ewih0q + (size_t)d * 1024 * 2816,
          partial + 16384, bsc1, d * 1024, 2760, 2816);
  for (int d = 0; d < 2; d++)
    addBf(obj_wih1 + (size_t)d * 512 * 1024, wih1T + (size_t)d * 1024 * 512,
          512, 1024, 1024, 512, 0, 0);
  for (int d = 0; d < 2; d++)
    addBf(edge_wih1 + (size_t)d * 512 * 1024, ewih1T + (size_t)d * 1024 * 512,
          512, 1024, 1024, 512, 0, 0);
  addBf(dec_w, decT, 2888, 151, 256, 2944, 512, 2376);
  s2.trEnd = base;
  s2.conf = conf; s2.perm = perm;
  setup2_kernel<<<dim3(base + 32), dim3(256), 0, stream>>>(s2);

  auto gemm = [&](const void* A, int lda, const void* B, int ldb, int K, int N,
                  float* oF, __hip_bfloat16* oB, int ldc, const float* bias) {
    int gy = (N + 127) / 128;
    gemm_kernel<<<dim3(32 * gy), dim3(256), 0, stream>>>(
        (const u16*)A, lda, (const u16*)B, ldb, K, N, gy, oF, oB, ldc, bias);
  };
  auto gemm_i8 = [&](const u8* A, int lda, const u8* B, int ldb, int K, int N,
                     const float* asc, const float* bsc,
                     __hip_bfloat16* oB, int ldc, const float* bias) {
    int gy = (N + 127) / 128;
    gemm_i8_kernel<<<dim3(32 * gy), dim3(256), 0, stream>>>(
        A, lda, B, ldb, K, N, gy, asc, bsc, oB, ldc, bias);
  };
  auto rec = [&](const __hip_bfloat16* P, const u32* wpk, int gat, int op,
                 __hip_bfloat16* ob, int old_, float* of, int fld, int foff) {
    rec_kernel<<<dim3(64), dim3(1024), 0, stream>>>(
        P, perm, wpk, (const uint4*)(wpk + 81920), (const float*)(wpk + 131072),
        gat, op, ob, old_, of, fld, foff);
  };

  // obj layer 0 (i8)
  gemm_i8(FEq, 2432, wih0q, 2432, 2432, 2048, ascFE, bsc0, Pbuf, 2048, obj_b0);
  rec(Pbuf, whh0pk, 1, 0, hseq, 512, nullptr, 0, 0);
  // obj layer 1 -> enc into FE cols [0,512)
  gemm(hseq, 512, wih1T, 512, 512, 2048, nullptr, Pbuf, 2048, obj_b1);
  rec(Pbuf, whh1pk, 0, 1, FE, FE_LD, nullptr, 0, 0);
  // decoder -> out cols [0,151)
  gemm(FE, FE_LD, decT, 2944, 2944, 151, out, nullptr, 663, dec_b);
  // fused argmax + edge build + quant
  argmax_edge_kernel<<<dim3(4096), dim3(256), 0, stream>>>(
      out, obj_embed2_w, obj_fmaps, FE, EDGEq, ascEDGE);
  // edge layer 0 (i8)
  gemm_i8(EDGEq, 2816, ewih0q, 2816, 2816, 2048, ascEDGE, bsc1, Pbuf, 2048, edge_b0);
  rec(Pbuf, ewhh0pk, 1, 0, hseq, 512, nullptr, 0, 0);
  // edge layer 1 -> out cols [151,663)
  gemm(hseq, 512, ewih1T, 512, 512, 2048, nullptr, Pbuf, 2048, edge_b1);
  rec(Pbuf, ewhh1pk, 0, 1, nullptr, 0, out, 663, 151);
}